// Round 7
// baseline (78.009 us; speedup 1.0000x reference)
//
#include <hip/hip_runtime.h>

// 3-layer GCN (DGL GraphConv norm='both'), N=50000, E=800000, feats 1->100->10->1.
// Round 7: rocprof showed hipMemsetAsync(2KB) dispatching a 40us
// fillBufferAligned kernel EVERY replay (larger than all our compute!).
// Replaced with a one-block k_zero kernel (~2us). Pipeline otherwise
// unchanged from r6: LDS-bucketed CSR build (98K global atomics total) +
// atomic-free fused gathers.

#define NT 256
#define K_BKT 250    // node buckets
#define R_NODES 200  // nodes per bucket (250*200 = 50000)
#define CAP 4096     // arena entries per bucket; E/K=3200 avg, +15.8 sigma
#define CHUNK 4096   // edges per k_bin block

// -------- zero the 2*K_BKT reservation counters (replaces hipMemsetAsync) ----

__global__ void k_zero(unsigned* __restrict__ p, int nwords) {
  int i = blockIdx.x * blockDim.x + threadIdx.x;
  if (i < nwords) p[i] = 0u;
}

// -------- pass 1: bin edges by dst-range and src-range --------

__global__ __launch_bounds__(NT) void k_bin(const int4* __restrict__ src4,
                                            const int4* __restrict__ dst4, int E4,
                                            unsigned* __restrict__ cur_d,
                                            unsigned* __restrict__ cur_s,
                                            unsigned* __restrict__ dstArena,
                                            unsigned short* __restrict__ srcArena) {
  __shared__ unsigned cnt_d[K_BKT], cnt_s[K_BKT];   // block counts -> later cursors
  __shared__ unsigned st_d[K_BKT], st_s[K_BKT];     // staging starts
  __shared__ unsigned gb_d[K_BKT], gb_s[K_BKT];     // reserved arena bases
  __shared__ unsigned scd[NT], scs[NT];
  __shared__ unsigned stg_d[CHUNK];                 // (src16 | dstlocal16)
  __shared__ unsigned short stgb_d[CHUNK];          // bucket of staged entry
  __shared__ unsigned short stg_s[CHUNK];           // srclocal
  __shared__ unsigned short stgb_s[CHUNK];
  int t = threadIdx.x;
  for (int k = t; k < K_BKT; k += NT) { cnt_d[k] = 0u; cnt_s[k] = 0u; }
  __syncthreads();

  int base4 = blockIdx.x * (CHUNK / 4);
  int4 sA[4], dA[4];
#pragma unroll
  for (int j = 0; j < 4; j++) {
    int e4 = base4 + j * NT + t;
    if (e4 < E4) { sA[j] = src4[e4]; dA[j] = dst4[e4]; }
    else { sA[j] = make_int4(-1, -1, -1, -1); dA[j] = make_int4(-1, -1, -1, -1); }
  }
  const int* sp = (const int*)sA;
  const int* dp = (const int*)dA;
#pragma unroll
  for (int j = 0; j < 16; j++) {
    if (dp[j] >= 0) {
      atomicAdd(&cnt_d[(unsigned)dp[j] / R_NODES], 1u);
      atomicAdd(&cnt_s[(unsigned)sp[j] / R_NODES], 1u);
    }
  }
  __syncthreads();
  unsigned vd = (t < K_BKT) ? cnt_d[t] : 0u;
  unsigned vs = (t < K_BKT) ? cnt_s[t] : 0u;
  scd[t] = vd; scs[t] = vs;
  __syncthreads();
  for (int off = 1; off < NT; off <<= 1) {
    unsigned ad = (t >= off) ? scd[t - off] : 0u;
    unsigned as = (t >= off) ? scs[t - off] : 0u;
    __syncthreads();
    scd[t] += ad; scs[t] += as;
    __syncthreads();
  }
  if (t < K_BKT) {
    st_d[t] = scd[t] - vd;
    st_s[t] = scs[t] - vs;
    gb_d[t] = vd ? atomicAdd(&cur_d[t], vd) : 0u;   // reserve arena space
    gb_s[t] = vs ? atomicAdd(&cur_s[t], vs) : 0u;
    cnt_d[t] = st_d[t];                              // become LDS cursors
    cnt_s[t] = st_s[t];
  }
  __syncthreads();
#pragma unroll
  for (int j = 0; j < 16; j++) {
    if (dp[j] >= 0) {
      unsigned d = (unsigned)dp[j], s = (unsigned)sp[j];
      unsigned bd = d / R_NODES;
      unsigned pd = atomicAdd(&cnt_d[bd], 1u);
      stg_d[pd] = (s & 0xFFFFu) | ((d - bd * R_NODES) << 16);
      stgb_d[pd] = (unsigned short)bd;
      unsigned bs = s / R_NODES;
      unsigned ps = atomicAdd(&cnt_s[bs], 1u);
      stg_s[ps] = (unsigned short)(s - bs * R_NODES);
      stgb_s[ps] = (unsigned short)bs;
    }
  }
  __syncthreads();
  int total = E4 * 4 - blockIdx.x * CHUNK;          // valid edges this block
  if (total > CHUNK) total = CHUNK;
  for (int j = t; j < total; j += NT) {             // coalesced-run copy-out
    unsigned b = stgb_d[j];
    unsigned off = gb_d[b] + ((unsigned)j - st_d[b]);
    if (off < CAP) dstArena[(size_t)b * CAP + off] = stg_d[j];
  }
  for (int j = t; j < total; j += NT) {
    unsigned b = stgb_s[j];
    unsigned off = gb_s[b] + ((unsigned)j - st_s[b]);
    if (off < CAP) srcArena[(size_t)b * CAP + off] = stg_s[j];
  }
}

// -------- pass 2: per-bucket CSR build + degrees + fused norm --------

__global__ __launch_bounds__(NT) void k_bucket(const unsigned* __restrict__ cur_d,
                                               const unsigned* __restrict__ cur_s,
                                               const unsigned* __restrict__ dstArena,
                                               const unsigned short* __restrict__ srcArena,
                                               const float* __restrict__ x,
                                               unsigned short* __restrict__ csr16,
                                               unsigned* __restrict__ rs, unsigned* __restrict__ rd,
                                               float* __restrict__ dsrc_inv,
                                               float* __restrict__ ddst_inv,
                                               float* __restrict__ s0, int n) {
  __shared__ unsigned cnt[R_NODES], cnts[R_NODES], start[R_NODES];
  __shared__ unsigned sc[NT];
  __shared__ unsigned short stage[CAP];
  int t = threadIdx.x, b = blockIdx.x;
  for (int k = t; k < R_NODES; k += NT) { cnt[k] = 0u; cnts[k] = 0u; }
  __syncthreads();
  unsigned nd = cur_d[b]; if (nd > CAP) nd = CAP;
  unsigned ns = cur_s[b]; if (ns > CAP) ns = CAP;
  const unsigned* darr = dstArena + (size_t)b * CAP;
  const unsigned short* sarr = srcArena + (size_t)b * CAP;
  for (unsigned i = t; i < nd; i += NT) atomicAdd(&cnt[darr[i] >> 16], 1u);
  for (unsigned i = t; i < ns; i += NT) atomicAdd(&cnts[sarr[i]], 1u);
  __syncthreads();
  unsigned v = (t < R_NODES) ? cnt[t] : 0u;
  sc[t] = v;
  __syncthreads();
  for (int off = 1; off < NT; off <<= 1) {
    unsigned a = (t >= off) ? sc[t - off] : 0u;
    __syncthreads();
    sc[t] += a;
    __syncthreads();
  }
  if (t < R_NODES) start[t] = sc[t] - v;
  __syncthreads();
  if (t < R_NODES) {
    int vg = b * R_NODES + t;
    if (vg < n) {
      unsigned di = cnt[t], dou = cnts[t];
      rs[vg] = (unsigned)b * CAP + start[t];
      rd[vg] = di;
      ddst_inv[vg] = rsqrtf((float)(di < 1u ? 1u : di));
      float ia = rsqrtf((float)(dou < 1u ? 1u : dou));
      dsrc_inv[vg] = ia;
      s0[vg] = x[vg] * ia;
    }
    cnt[t] = start[t];  // cursor
  }
  __syncthreads();
  for (unsigned i = t; i < nd; i += NT) {
    unsigned e = darr[i];
    unsigned pos = atomicAdd(&cnt[e >> 16], 1u);
    stage[pos] = (unsigned short)(e & 0xFFFFu);
  }
  __syncthreads();
  unsigned short* outp = csr16 + (size_t)b * CAP;
  for (unsigned i = t; i < nd; i += NT) outp[i] = stage[i];  // coalesced
}

// -------- fused gather + compute stages (all atomic-free) --------

__global__ void k_g_l0l1(const unsigned* __restrict__ rs, const unsigned* __restrict__ rd,
                         const unsigned short* __restrict__ csr16,
                         const float* __restrict__ s0,
                         const float* __restrict__ dsrc_inv, const float* __restrict__ ddst_inv,
                         const float* __restrict__ W0, const float* __restrict__ b0,
                         const float* __restrict__ W1,
                         float* __restrict__ t1, int n) {
  __shared__ float W0s[100], b0s[100], W1s[1000];
  for (int k = threadIdx.x; k < 100; k += blockDim.x) { W0s[k] = W0[k]; b0s[k] = b0[k]; }
  for (int k = threadIdx.x; k < 1000; k += blockDim.x) W1s[k] = W1[k];
  __syncthreads();
  int tid = blockIdx.x * blockDim.x + threadIdx.x;
  int v = tid >> 2, k = tid & 3;
  if (v >= n) return;
  unsigned base = rs[v], deg = rd[v];
  const unsigned short* row = csr16 + base;
  float c = 0.0f;
#pragma unroll 4
  for (unsigned i = k; i < deg; i += 4) c += s0[row[i]];
  c += __shfl_xor(c, 1, 4);
  c += __shfl_xor(c, 2, 4);
  c *= ddst_inv[v];
  float t[10];
#pragma unroll
  for (int j = 0; j < 10; j++) t[j] = 0.0f;
  for (int f = k; f < 100; f += 4) {
    float a = c * W0s[f] + b0s[f];
    a = a >= 0.0f ? a : 0.01f * a;  // leaky_relu(0.01)
#pragma unroll
    for (int j = 0; j < 10; j++) t[j] += a * W1s[f * 10 + j];
  }
#pragma unroll
  for (int j = 0; j < 10; j++) {
    t[j] += __shfl_xor(t[j], 1, 4);
    t[j] += __shfl_xor(t[j], 2, 4);
  }
  float so = dsrc_inv[v];
  for (int j = k; j < 10; j += 4) t1[v * 10 + j] = t[j] * so;
}

__global__ void k_g10_l1l2(const unsigned* __restrict__ rs, const unsigned* __restrict__ rd,
                           const unsigned short* __restrict__ csr16,
                           const float* __restrict__ t1,
                           const float* __restrict__ dsrc_inv, const float* __restrict__ ddst_inv,
                           const float* __restrict__ b1, const float* __restrict__ W2,
                           float* __restrict__ t2, int n) {
  int tid = blockIdx.x * blockDim.x + threadIdx.x;
  int v = tid >> 4, f = tid & 15;
  if (v >= n) return;
  unsigned base = rs[v], deg = rd[v];
  const unsigned short* row = csr16 + base;
  // register row cache (first 48 slots; csr16 is padded so OOB reads are safe)
  int r0 = row[f];
  int r1 = row[f + 16];
  int r2 = row[f + 32];
  float acc = 0.0f;
  for (unsigned i = 0; i < deg; i++) {
    int sv;
    if (i < 48u) {
      int which = i >> 4;
      int rsel = (which == 0) ? r0 : ((which == 1) ? r1 : r2);
      sv = __shfl(rsel, (int)(i & 15u), 16);
    } else {
      sv = row[i];  // astronomically rare (deg>48)
    }
    float val = (f < 10) ? t1[(unsigned)sv * 10 + f] : 0.0f;
    acc += val;
  }
  float p = 0.0f;
  if (f < 10) {
    float h = acc * ddst_inv[v] + b1[f];
    h = h > 0.0f ? h : 0.0f;  // relu
    p = h * W2[f];
  }
  p += __shfl_xor(p, 1, 16);
  p += __shfl_xor(p, 2, 16);
  p += __shfl_xor(p, 4, 16);
  p += __shfl_xor(p, 8, 16);
  if (f == 0) t2[v] = p * dsrc_inv[v];
}

__global__ void k_g_out(const unsigned* __restrict__ rs, const unsigned* __restrict__ rd,
                        const unsigned short* __restrict__ csr16,
                        const float* __restrict__ t2, const float* __restrict__ ddst_inv,
                        const float* __restrict__ b2, float* __restrict__ out, int n) {
  int tid = blockIdx.x * blockDim.x + threadIdx.x;
  int v = tid >> 2, k = tid & 3;
  if (v >= n) return;
  unsigned base = rs[v], deg = rd[v];
  const unsigned short* row = csr16 + base;
  float c = 0.0f;
#pragma unroll 4
  for (unsigned i = k; i < deg; i += 4) c += t2[row[i]];
  c += __shfl_xor(c, 1, 4);
  c += __shfl_xor(c, 2, 4);
  if (k == 0) {
    float h = c * ddst_inv[v] + b2[0];
    out[v] = h > 0.0f ? h : 0.0f;
  }
}

extern "C" void kernel_launch(void* const* d_in, const int* in_sizes, int n_in,
                              void* d_out, int out_size, void* d_ws, size_t ws_size,
                              hipStream_t stream) {
  const float* in_feat = (const float*)d_in[0];
  const int* ei = (const int*)d_in[1];
  const float* W0 = (const float*)d_in[2];
  const float* b0 = (const float*)d_in[3];
  const float* W1 = (const float*)d_in[4];
  const float* b1 = (const float*)d_in[5];
  const float* W2 = (const float*)d_in[6];
  const float* b2 = (const float*)d_in[7];
  float* out = (float*)d_out;

  const int n = in_sizes[0];      // 50000 (= K_BKT * R_NODES)
  const int E = in_sizes[1] / 2;  // 800000 (divisible by 4)
  const int* src = ei;
  const int* dst = ei + E;

  // Workspace layout (4-byte words unless noted). Only cur_d/cur_s zeroed.
  unsigned* cur_d = (unsigned*)d_ws;                         // K_BKT
  unsigned* cur_s = cur_d + K_BKT;                           // K_BKT
  unsigned* dstArena = cur_s + K_BKT;                        // K_BKT*CAP u32
  unsigned short* srcArena = (unsigned short*)(dstArena + (size_t)K_BKT * CAP);  // K*CAP u16
  unsigned short* csr16 = srcArena + (size_t)K_BKT * CAP;    // K*CAP + 64 u16 (pad)
  unsigned* rs = (unsigned*)(csr16 + (size_t)K_BKT * CAP + 64);
  unsigned* rd = rs + n;                                     // n
  float* dsrc_inv = (float*)(rd + n);                        // n
  float* ddst_inv = dsrc_inv + n;                            // n
  float* s0 = ddst_inv + n;                                  // n
  float* t1 = s0 + n;                                        // 10n
  float* t2 = t1 + 10 * n;                                   // n

  const int E4 = E / 4;
  const int binBlocks = (E + CHUNK - 1) / CHUNK;

  k_zero<<<2, NT, 0, stream>>>(cur_d, 2 * K_BKT);
  k_bin<<<binBlocks, NT, 0, stream>>>((const int4*)src, (const int4*)dst, E4,
                                      cur_d, cur_s, dstArena, srcArena);
  k_bucket<<<K_BKT, NT, 0, stream>>>(cur_d, cur_s, dstArena, srcArena, in_feat,
                                     csr16, rs, rd, dsrc_inv, ddst_inv, s0, n);
  k_g_l0l1<<<(4 * n + NT - 1) / NT, NT, 0, stream>>>(rs, rd, csr16, s0, dsrc_inv, ddst_inv,
                                                     W0, b0, W1, t1, n);
  k_g10_l1l2<<<(16 * n + NT - 1) / NT, NT, 0, stream>>>(rs, rd, csr16, t1, dsrc_inv, ddst_inv,
                                                        b1, W2, t2, n);
  k_g_out<<<(4 * n + NT - 1) / NT, NT, 0, stream>>>(rs, rd, csr16, t2, ddst_inv, b2, out, n);
}